// Round 1
// baseline (583.338 us; speedup 1.0000x reference)
//
#include <hip/hip_runtime.h>

// Problem constants (from reference): x is (B=8, C=128, H=64, W=64) fp32, KERNEL=2.
// out[b, i, j, p] = x[b, j, idx(b, i, p)], p in [0, 1024)  -> out is (8,128,128,1024).
#define BATCH 8
#define CH    128
#define HH    64
#define WW    64
#define HP    32           // HH/2
#define WP    32           // WW/2
#define NP    1024         // HP*WP windows per plane
#define PLANE 4096         // HH*WW elems per plane

__global__ __launch_bounds__(256)
void pool_gather_kernel(const float* __restrict__ x, float* __restrict__ out) {
    const int b = blockIdx.x;   // 0..7  (fastest-varying -> spreads b across XCDs)
    const int i = blockIdx.y;   // 0..127 argmax channel
    const int t = threadIdx.x;  // 0..255

    const float* planeI = x + ((size_t)(b * CH + i) << 12);  // x[b, i] : 4096 floats

    // Phase 1: this thread computes argmax flat-indices for windows p = t + 256k.
    // Window element order (row-major) 0=(0,0) 1=(0,1) 2=(1,0) 3=(1,1); strict '>'
    // keeps the FIRST occurrence of the max, matching jnp/np argmax semantics.
    int idx[4];
#pragma unroll
    for (int k = 0; k < 4; ++k) {
        const int p  = t + (k << 8);
        const int hp = p >> 5;          // window row
        const int wp = p & 31;          // window col
        // rows 2*hp and 2*hp+1; element offset of row 2*hp is hp*128 (8B-aligned)
        const float2* r0 = (const float2*)(planeI + (hp << 7));
        const float2* r1 = (const float2*)(planeI + (hp << 7) + WW);
        const float2 topv = r0[wp];
        const float2 botv = r1[wp];
        float m = topv.x; int a = 0;
        if (topv.y > m) { m = topv.y; a = 1; }
        if (botv.x > m) { m = botv.x; a = 2; }
        if (botv.y > m) { m = botv.y; a = 3; }
        const int row = (hp << 1) + (a >> 1);
        const int col = (wp << 1) + (a & 1);
        idx[k] = (row << 6) + col;      // flat index into the 64x64 plane
    }

    // Phase 2: gather all 128 channels at these indices; fully coalesced stores.
    const float* planeB  = x + ((size_t)(b * CH) << 12);              // x[b, 0]
    float*       outBase = out + (((size_t)(b * CH + i) * CH) << 10) + t;

    for (int j = 0; j < CH; ++j) {
        const float* pj = planeB + ((size_t)j << 12);
        // 4 independent gathers -> MLP; addresses of one wave span ~4 image rows.
        const float v0 = pj[idx[0]];
        const float v1 = pj[idx[1]];
        const float v2 = pj[idx[2]];
        const float v3 = pj[idx[3]];
        float* o = outBase + ((size_t)j << 10);
        o[0]   = v0;
        o[256] = v1;
        o[512] = v2;
        o[768] = v3;
    }
}

extern "C" void kernel_launch(void* const* d_in, const int* in_sizes, int n_in,
                              void* d_out, int out_size, void* d_ws, size_t ws_size,
                              hipStream_t stream) {
    const float* x  = (const float*)d_in[0];
    float*       out = (float*)d_out;
    dim3 grid(BATCH, CH);   // (8, 128) blocks; b fastest -> XCD-pinned L2 reuse of x[b]
    pool_gather_kernel<<<grid, 256, 0, stream>>>(x, out);
}

// Round 2
// 558.695 us; speedup vs baseline: 1.0441x; 1.0441x over previous
//
#include <hip/hip_runtime.h>

// x: (B=8, C=128, H=64, W=64) fp32; KERNEL=2.
// out[b,i,j,p] = x[b, j, argmax-window-p of x[b,i]]  -> out (8,128,128,1024) fp32.
#define BATCH 8
#define CH    128
#define G     8      // i-channels per block
#define JC    32     // j-channels per block
#define PLANE 4096   // 64*64 floats per plane (16 KB)

__global__ __launch_bounds__(256)
void pool_gather_kernel(const float* __restrict__ x, float* __restrict__ out) {
    __shared__ float buf[2][PLANE];          // 32 KB double buffer
    const int b  = blockIdx.x;               // 0..7  (fastest -> b pinned per XCD)
    const int ig = blockIdx.y;               // 0..15 i-group
    const int jc = blockIdx.z;               // 0..3  j-chunk
    const int t  = threadIdx.x;              // 0..255

    // ---- Phase 1: argmax indices for G channels, windows p = t + 256k -------
    // Window elems row-major (0,0)(0,1)(1,0)(1,1); strict '>' keeps FIRST max,
    // matching jnp.argmax (verified absmax 0 in R1).
    int idx[G][4];
    for (int g = 0; g < G; ++g) {
        const float* planeI = x + ((size_t)(b * CH + ig * G + g) << 12);
#pragma unroll
        for (int k = 0; k < 4; ++k) {
            const int p  = t + (k << 8);
            const int hp = p >> 5;
            const int wp = p & 31;
            const float2 topv = ((const float2*)(planeI + (hp << 7)))[wp];
            const float2 botv = ((const float2*)(planeI + (hp << 7) + 64))[wp];
            float m = topv.x; int a = 0;
            if (topv.y > m) { m = topv.y; a = 1; }
            if (botv.x > m) { m = botv.x; a = 2; }
            if (botv.y > m) { m = botv.y; a = 3; }
            idx[g][k] = (((hp << 1) + (a >> 1)) << 6) + (wp << 1) + (a & 1);
        }
    }

    const float* planeB = x + ((size_t)(b * CH) << 12);
    const int j0 = jc * JC;

    // ---- Phase 2: double-buffered LDS staging + LDS gather + coalesced store
    {   // prefetch plane j0 into buf[0]: 256 thr * 4 float4 = 16 KB, coalesced
        const float4* src = (const float4*)(planeB + ((size_t)j0 << 12));
        float4* dst = (float4*)buf[0];
#pragma unroll
        for (int c = 0; c < 4; ++c) dst[t + (c << 8)] = src[t + (c << 8)];
    }

    for (int jj = 0; jj < JC; ++jj) {
        __syncthreads();                     // buf[cur] ready for all waves
        const int cur = jj & 1;
        if (jj + 1 < JC) {                   // stage next plane into other buf
            const float4* src = (const float4*)(planeB + ((size_t)(j0 + jj + 1) << 12));
            float4* dst = (float4*)buf[cur ^ 1];
#pragma unroll
            for (int c = 0; c < 4; ++c) dst[t + (c << 8)] = src[t + (c << 8)];
        }
        const float* bp = buf[cur];
#pragma unroll
        for (int g = 0; g < G; ++g) {
            // LDS gather: bank = (2*(t&31)+dw) % 32 -> 2-4 lanes/bank (cheap)
            const float v0 = bp[idx[g][0]];
            const float v1 = bp[idx[g][1]];
            const float v2 = bp[idx[g][2]];
            const float v3 = bp[idx[g][3]];
            float* o = out + (((size_t)((b * CH + ig * G + g) * CH + j0 + jj)) << 10) + t;
            o[0]   = v0;                     // 4 coalesced 256B wave-stores
            o[256] = v1;
            o[512] = v2;
            o[768] = v3;
        }
    }
}

extern "C" void kernel_launch(void* const* d_in, const int* in_sizes, int n_in,
                              void* d_out, int out_size, void* d_ws, size_t ws_size,
                              hipStream_t stream) {
    const float* x   = (const float*)d_in[0];
    float*       out = (float*)d_out;
    dim3 grid(BATCH, CH / G, CH / JC);       // (8,16,4) = 512 blocks, 2/CU
    pool_gather_kernel<<<grid, 256, 0, stream>>>(x, out);
}